// Round 8
// baseline (146.014 us; speedup 1.0000x reference)
//
#include <hip/hip_runtime.h>
#include <hip/hip_bf16.h>
#include <math.h>

// Problem constants
#define BB    8
#define HH    160
#define WW    256
#define CC    700
#define KK    250
#define NBINS 750
#define NHIST 30
#define NJIT  60
#define NFRM  90
#define PP    (HH*WW)      // 40960
#define TOUT  500
#define MAGIC (400.0f/750.0f)

// GEMM dims
#define MPAD  512
#define NPAD  768
#define NKT   1280         // K / 32
#define KSPLIT 40          // z slices of 1024 px
#define NT    11           // 11 x 64 = 704 >= 700 cols

typedef __attribute__((ext_vector_type(8))) short short8;
typedef __attribute__((ext_vector_type(4))) float f32x4;

__device__ __forceinline__ unsigned short f2bf(float x) {
    unsigned u = __builtin_bit_cast(unsigned, x);
    u += 0x7fffu + ((u >> 16) & 1u);   // RNE
    return (unsigned short)(u >> 16);
}

// LDS byte-offset swizzle (involution, XORs bits 8-10 into bank bits 4-6)
__device__ __forceinline__ int SWZ(int X) { return X ^ (((X >> 8) & 7) << 4); }

// ---------------------------------------------------------------------------
// pack_a: jittered image -> bf16 fragment-ready layout via LDS transpose.
// Ap[((mt*1280 + kt)*64 + l)*8 + j] = A[mt*16 + (l&15)][kt*32 + 8*(l>>4) + j]
// ---------------------------------------------------------------------------
__global__ __launch_bounds__(256) void pack_a(
    const float* __restrict__ img, const int* __restrict__ eye,
    unsigned short* __restrict__ Ap)
{
    __shared__ unsigned short lds[8192];   // 16KB
    const int t = threadIdx.x, w = t >> 6, l = t & 63;
    const int mt = blockIdx.x;             // 0..31
    const int ch = blockIdx.y;             // 0..19

    int rb[4], rdy[4], rdx[4]; bool rvk[4];
    #pragma unroll
    for (int sub = 0; sub < 4; ++sub) {
        int r = sub*4 + w, m = mt*16 + r;
        rvk[sub] = (m < 480);
        int b = 0, dy = 0, dx = 0;
        if (rvk[sub]) {
            b = m / 60; int f = m % 60;
            dy = eye[(b*NJIT + f)*2 + 0];
            dx = eye[(b*NJIT + f)*2 + 1];
        }
        rb[sub] = b; rdy[sub] = dy; rdx[sub] = dx;
    }

    for (int q = 0; q < 4; ++q) {
        const int kt0   = (ch*4 + q)*16;
        const int kbase = kt0 * 32;
        #pragma unroll
        for (int sub = 0; sub < 4; ++sub) {
            int r = sub*4 + w;
            const float* imgb = img + (size_t)rb[sub]*PP;
            #pragma unroll
            for (int h = 0; h < 2; ++h) {
                int ir = (kbase >> 8) + h + rdy[sub];
                bool ok = rvk[sub] && (ir < HH);
                #pragma unroll
                for (int qq = 0; qq < 4; ++qq) {
                    int cc2 = qq*64 + l + rdx[sub];
                    float v = 0.f;
                    if (ok && cc2 < WW) v = imgb[ir*WW + cc2];   // coalesced
                    int pl = h*256 + qq*64 + l;
                    int X = ((pl>>5)<<10) | (((pl>>3)&3)<<8) | (r<<4) | ((pl&7)<<1);
                    *(unsigned short*)((char*)lds + SWZ(X)) = f2bf(v);
                }
            }
        }
        __syncthreads();
        unsigned short* outp = Ap + ((size_t)mt*NKT + kt0)*512;
        #pragma unroll
        for (int i = 0; i < 4; ++i) {
            int X = i*4096 + t*16;             // 1KB/wave contiguous stores
            short8 v = *(const short8*)((const char*)lds + SWZ(X));
            *(short8*)((char*)outp + X) = v;
        }
        __syncthreads();
    }
}

// ---------------------------------------------------------------------------
// gemm_bf: C += A(bf16 packed) x B(fp32 filt, converted inline).
// BM=512 (B read ONCE), BN=64, BK=64. 256 thr = 4 waves, wave = 128x64
// (acc[2][4][4]). grid = 440 blocks = 8 xcd x (5 zq x 11 nt); blocks
// sharing a z-slice share bid&7 -> same XCD L2. Two blocks/CU co-resident.
// A: 16 frag loads batch-issued per step (one latency exposure).
// Bs: double-buffered 2x8KB, SWZ frag layout (write 2-way=free, read
// conflict-free), ONE barrier per step.
// ---------------------------------------------------------------------------
__global__ __launch_bounds__(256) void gemm_bf(
    const unsigned short* __restrict__ Ap, const float* __restrict__ filt,
    float* __restrict__ part)
{
    __shared__ unsigned short Bs[2][4096];   // 2 x 8KB

    const int t = threadIdx.x, l = t & 63, w = t >> 6;
    const int bid = blockIdx.x;
    const int q  = bid >> 3;
    const int z  = (bid & 7) + 8*(q/NT);
    const int nt = q % NT;
    const int n0 = nt*64;

    // B staging: thread t -> row = t>>2 (0..63), px0 = (t&3)*16
    const int brow = t >> 2;
    const bool bok = (n0 + brow) < CC;
    const int px0  = (t & 3) * 16;
    const float* rp = filt + (size_t)(bok ? n0 + brow : 0)*PP + (size_t)z*1024 + px0;
    int wXa, wXb;
    {
        int c0 = px0 >> 3, c1 = c0 + 1;
        wXa = SWZ(((brow>>4)<<11) | ((c0>>2)<<10) | ((c0&3)<<8) | ((brow&15)<<4));
        wXb = SWZ(((brow>>4)<<11) | ((c1>>2)<<10) | ((c1&3)<<8) | ((brow&15)<<4));
    }

    f32x4 acc[2][4][4] = {};

    // prologue: stage B(0) -> Bs[0]
    {
        float4 bv[4];
        #pragma unroll
        for (int j = 0; j < 4; ++j)
            bv[j] = bok ? *(const float4*)(rp + j*4) : make_float4(0.f,0.f,0.f,0.f);
        short8 p0, p1;
        p0[0]=(short)f2bf(bv[0].x); p0[1]=(short)f2bf(bv[0].y);
        p0[2]=(short)f2bf(bv[0].z); p0[3]=(short)f2bf(bv[0].w);
        p0[4]=(short)f2bf(bv[1].x); p0[5]=(short)f2bf(bv[1].y);
        p0[6]=(short)f2bf(bv[1].z); p0[7]=(short)f2bf(bv[1].w);
        p1[0]=(short)f2bf(bv[2].x); p1[1]=(short)f2bf(bv[2].y);
        p1[2]=(short)f2bf(bv[2].z); p1[3]=(short)f2bf(bv[2].w);
        p1[4]=(short)f2bf(bv[3].x); p1[5]=(short)f2bf(bv[3].y);
        p1[6]=(short)f2bf(bv[3].z); p1[7]=(short)f2bf(bv[3].w);
        *(short8*)((char*)Bs[0] + wXa) = p0;
        *(short8*)((char*)Bs[0] + wXb) = p1;
    }
    __syncthreads();

    // wave w owns A tiles mt = w*8 .. w*8+7
    const unsigned short* abase =
        Ap + ((size_t)(w*8)*NKT + (size_t)z*32)*512 + (size_t)l*8;

    for (int step = 0; step < 16; ++step) {
        // ---- A: batch-issue all 16 frag loads for this step
        short8 a[16];
        #pragma unroll
        for (int i = 0; i < 8; ++i) {
            const unsigned short* ai = abase + ((size_t)i*NKT + step*2)*512;
            a[i*2+0] = *(const short8*)(ai);
            a[i*2+1] = *(const short8*)(ai + 512);
        }
        // ---- B(step+1): issued last (A consumption won't force their drain)
        float4 bv[4];
        if (step < 15) {
            #pragma unroll
            for (int j = 0; j < 4; ++j)
                bv[j] = bok ? *(const float4*)(rp + (step+1)*64 + j*4)
                            : make_float4(0.f,0.f,0.f,0.f);
        }
        // ---- compute from Bs[step&1]
        const char* bsb = (const char*)Bs[step & 1];
        #pragma unroll
        for (int ktb = 0; ktb < 2; ++ktb) {
            short8 breg[4];
            #pragma unroll
            for (int j = 0; j < 4; ++j) {
                int Xr = (j<<11) | (ktb<<10) | ((l>>4)<<8) | ((l&15)<<4);
                breg[j] = *(const short8*)(bsb + SWZ(Xr));
            }
            #pragma unroll
            for (int i = 0; i < 8; ++i)
                #pragma unroll
                for (int j = 0; j < 4; ++j)
                    acc[i>>2][i&3][j] = __builtin_amdgcn_mfma_f32_16x16x32_bf16(
                        a[i*2+ktb], breg[j], acc[i>>2][i&3][j], 0, 0, 0);
        }
        // ---- stage B(step+1) -> other buffer (MFMA phase covered B latency)
        if (step < 15) {
            char* bsw = (char*)Bs[(step+1) & 1];
            short8 p0, p1;
            p0[0]=(short)f2bf(bv[0].x); p0[1]=(short)f2bf(bv[0].y);
            p0[2]=(short)f2bf(bv[0].z); p0[3]=(short)f2bf(bv[0].w);
            p0[4]=(short)f2bf(bv[1].x); p0[5]=(short)f2bf(bv[1].y);
            p0[6]=(short)f2bf(bv[1].z); p0[7]=(short)f2bf(bv[1].w);
            p1[0]=(short)f2bf(bv[2].x); p1[1]=(short)f2bf(bv[2].y);
            p1[2]=(short)f2bf(bv[2].z); p1[3]=(short)f2bf(bv[2].w);
            p1[4]=(short)f2bf(bv[3].x); p1[5]=(short)f2bf(bv[3].y);
            p1[6]=(short)f2bf(bv[3].z); p1[7]=(short)f2bf(bv[3].w);
            *(short8*)(bsw + wXa) = p0;
            *(short8*)(bsw + wXb) = p1;
        }
        __syncthreads();
    }

    // epilogue: C/D layout col = l&15, row = (l>>4)*4 + reg
    const int rbase = (l >> 4)*4, cl = l & 15;
    #pragma unroll
    for (int h = 0; h < 2; ++h)
        #pragma unroll
        for (int i = 0; i < 4; ++i)
            #pragma unroll
            for (int j = 0; j < 4; ++j) {
                int m = w*128 + h*64 + i*16 + rbase;
                int n = n0 + j*16 + cl;
                float* p = part + ((size_t)z*MPAD + m)*NPAD + n;
                #pragma unroll
                for (int r = 0; r < 4; ++r) p[(size_t)r*NPAD] = acc[h][i][j][r];
            }
}

// ---------------------------------------------------------------------------
// build_spat: spat[b][fr][c] = history (fr<30) | sum of KSPLIT partials
// ---------------------------------------------------------------------------
__global__ __launch_bounds__(256) void build_spat(
    const float* __restrict__ hist, const float* __restrict__ part,
    float* __restrict__ spat)
{
    int idx = blockIdx.x*256 + threadIdx.x;
    if (idx >= BB*NFRM*CC) return;
    int c   = idx % CC;
    int rem = idx / CC;
    int fr  = rem % NFRM;
    int b   = rem / NFRM;
    float v;
    if (fr < NHIST) {
        v = hist[(b*NHIST + fr)*CC + c];
    } else {
        int m = b*NJIT + (fr - NHIST);
        v = 0.f;
        #pragma unroll
        for (int kp = 0; kp < KSPLIT; ++kp)
            v += part[((size_t)kp*MPAD + m)*NPAD + c];
    }
    spat[idx] = v;
}

// ---------------------------------------------------------------------------
// conv_loss: per (b,c) gather+upsample -> depthwise conv (chunked-8 rolling
// window, all-static register indexing) -> loss partial. One wave per block.
// ---------------------------------------------------------------------------
__global__ __launch_bounds__(64) void conv_loss(
    const float* __restrict__ spat, const int* __restrict__ sel,
    const float* __restrict__ wts,  const float* __restrict__ tc,
    const float* __restrict__ fb,   const float* __restrict__ spk,
    const float* __restrict__ tmask, float* __restrict__ lpart)
{
    __shared__ float tcs[256];
    __shared__ float ups[864];   // index t + (t>>3): conflict-free sliding window

    const int lane = threadIdx.x;
    const int c = blockIdx.x;
    const int b = blockIdx.y;

    for (int k = lane; k < 256; k += 64)
        tcs[k] = (k < KK) ? tc[c*KK + k] : 0.f;

    const float* spb = spat + (size_t)b*NFRM*CC + c;
    for (int tt = lane; tt < 768; tt += 64) {
        float v = 0.f;
        if (tt < NBINS) {
            int base = (b*NBINS + tt)*2;
            int s0 = sel[base], s1 = sel[base+1];
            float w0 = wts[base], w1 = wts[base+1];
            v = w0 * spb[s0*CC] + w1 * spb[s1*CC];
        }
        ups[tt + (tt >> 3)] = v;
    }
    __syncthreads();

    const int t0 = lane * 8;
    float u[16];
    #pragma unroll
    for (int j = 0; j < 16; ++j) { int q = t0 + j; u[j] = ups[q + (q >> 3)]; }

    float acc[8] = {};
    #pragma unroll 4
    for (int kc = 0; kc < 248; kc += 8) {
        #pragma unroll
        for (int kk = 0; kk < 8; ++kk) {
            float w2 = tcs[kc + kk];
            #pragma unroll
            for (int j = 0; j < 8; ++j) acc[j] += w2 * u[kk + j];
        }
        #pragma unroll
        for (int j = 0; j < 8; ++j) u[j] = u[j + 8];
        #pragma unroll
        for (int j = 0; j < 8; ++j) {
            int q = t0 + kc + 16 + j;
            u[j + 8] = ups[q + (q >> 3)];
        }
    }
    #pragma unroll
    for (int kk = 0; kk < 8; ++kk) {
        float w2 = tcs[248 + kk];
        #pragma unroll
        for (int j = 0; j < 8; ++j) acc[j] += w2 * u[kk + j];
    }

    const size_t bc = (size_t)b*CC + c;
    const float* fbp = fb  + bc*(TOUT+1);
    const float* sp  = spk + bc*NBINS + KK;
    const float* tm  = tmask + (size_t)b*TOUT;
    float lsum = 0.f;
    #pragma unroll
    for (int j = 0; j < 8; ++j) {
        int tt = t0 + j;
        if (tt < TOUT) {
            float g  = acc[j] + fbp[tt];
            float sv = sp[tt];
            lsum += (__expf(g) - sv*g) * tm[tt];
        }
    }
    #pragma unroll
    for (int off = 32; off > 0; off >>= 1)
        lsum += __shfl_down(lsum, off);
    if (lane == 0) lpart[bc] = lsum * MAGIC;
}

__global__ __launch_bounds__(256) void reduce_out(
    const float* __restrict__ lpart, float* __restrict__ out)
{
    __shared__ float red[256];
    int b = blockIdx.x, t = threadIdx.x;
    float s = 0.f;
    for (int i = t; i < CC; i += 256) s += lpart[(size_t)b*CC + i];
    red[t] = s; __syncthreads();
    for (int o = 128; o > 0; o >>= 1) {
        if (t < o) red[t] += red[t+o];
        __syncthreads();
    }
    if (t == 0) out[b] = red[0];
}

extern "C" void kernel_launch(void* const* d_in, const int* in_sizes, int n_in,
                              void* d_out, int out_size, void* d_ws, size_t ws_size,
                              hipStream_t stream) {
    const float* image = (const float*)d_in[0];
    const float* spk   = (const float*)d_in[1];
    const int*   eye   = (const int*)d_in[2];
    const float* tmask = (const float*)d_in[3];
    const int*   sel   = (const int*)d_in[4];
    const float* wts   = (const float*)d_in[5];
    const float* filt  = (const float*)d_in[6];
    const float* tc    = (const float*)d_in[7];
    const float* fb    = (const float*)d_in[8];
    const float* hist  = (const float*)d_in[9];
    float* out = (float*)d_out;

    unsigned short* Ap = (unsigned short*)d_ws;                 // 512*40960 bf16
    float* part  = (float*)(Ap + (size_t)MPAD*PP);              // 40*512*768 f32
    float* spat  = part + (size_t)KSPLIT*MPAD*NPAD;             // 8*90*700 f32
    float* lpart = spat + (size_t)BB*NFRM*CC;                   // 8*700 f32

    pack_a   <<<dim3(32, 20), 256, 0, stream>>>(image, eye, Ap);
    gemm_bf  <<<dim3(8*5*NT), 256, 0, stream>>>(Ap, filt, part);
    build_spat<<<dim3((BB*NFRM*CC + 255)/256), 256, 0, stream>>>(hist, part, spat);
    conv_loss<<<dim3(CC, BB), 64, 0, stream>>>(spat, sel, wts, tc, fb, spk, tmask, lpart);
    reduce_out<<<dim3(BB), 256, 0, stream>>>(lpart, out);
}

// Round 9
// 130.277 us; speedup vs baseline: 1.1208x; 1.1208x over previous
//
#include <hip/hip_runtime.h>
#include <hip/hip_bf16.h>
#include <math.h>

// Problem constants
#define BB    8
#define HH    160
#define WW    256
#define CC    700
#define KK    250
#define NBINS 750
#define NHIST 30
#define NJIT  60
#define NFRM  90
#define PP    (HH*WW)      // 40960
#define TOUT  500
#define MAGIC (400.0f/750.0f)

// GEMM dims (fp8 path)
#define MPAD   512
#define NPAD   768
#define KPTOT  640         // K / 64  (ktpairs)
#define KSPLIT 20
#define KPZ    32          // ktpairs per z slice (2048 px)
#define NSTEP  32
#define BSCALE     64.0f   // filter pre-scale (keeps fp8 out of subnormals)
#define INV_BSCALE (1.0f/64.0f)
#define PA_BLKS (32*80)
#define PB_BLKS (48*80)

typedef __attribute__((ext_vector_type(8))) short short8;
typedef __attribute__((ext_vector_type(4))) float f32x4;

// f32 -> OCP e4m3fn, RNE, flush-to-zero below 2^-6 (values there are
// negligible for our scaled operands), clamp to +-448.
__device__ __forceinline__ unsigned char f2fp8(float x) {
    x = fminf(fmaxf(x, -440.f), 440.f);
    unsigned u = __builtin_bit_cast(unsigned, x);
    unsigned s = (u >> 24) & 0x80u;
    int e = (u >> 23) & 0xFF;
    if (e < 121) return (unsigned char)s;            // |x| < 2^-6 -> 0
    unsigned u2 = u + 0x7FFFFu + ((u >> 20) & 1u);   // RNE at mantissa bit 20
    int e2 = (u2 >> 23) & 0xFF;
    unsigned m = (u2 >> 20) & 7u;
    if (e2 > 135 || (e2 == 135 && m == 7u)) return (unsigned char)(s | 0x7E);
    return (unsigned char)(s | ((unsigned)(e2 - 120) << 3) | m);
}

__device__ __forceinline__ void gload16(const void* g, void* l) {
    __builtin_amdgcn_global_load_lds(
        (const __attribute__((address_space(1))) unsigned int*)g,
        (__attribute__((address_space(3))) unsigned int*)l, 16, 0, 0);
}

// LDS byte-offset swizzle (involution; XORs bits 8-10 into bank bits 4-6)
__device__ __forceinline__ int SWZ(int X) { return X ^ (((X >> 8) & 7) << 4); }

// Fragment-ready fp8 layout, per 16-row tile and ktpair (64 px) 1KB block:
//   byte(r, px) = kp*1024 + (r + 16*((px>>3)&3))*16 + ((px>>5)&1)*8 + (px&7)
// so lane l = r + 16*pg holds [kt-even 8B | kt-odd 8B] -> one ds_read_b128
// feeds both K=32 MFMA halves.
__device__ __forceinline__ int FRX(int r, int pl) {
    return ((pl >> 6) << 10) | ((((pl >> 3) & 3) * 16 + r) << 4)
         | (((pl >> 5) & 1) << 3) | (pl & 7);
}

// ---------------------------------------------------------------------------
// pack_ab: A (jittered image) and B (filters x64) -> fp8 fragment layout via
// LDS transpose. Coalesced reads, SWZ'd LDS (<=2-way except A's b8 ~4-way),
// contiguous 1KB/wave output stores.
// ---------------------------------------------------------------------------
__global__ __launch_bounds__(256) void pack_ab(
    const float* __restrict__ img, const int* __restrict__ eye,
    const float* __restrict__ filt,
    unsigned char* __restrict__ Ap, unsigned char* __restrict__ Bp)
{
    __shared__ unsigned char lds[8192];
    const int t = threadIdx.x, w = t >> 6, l = t & 63;
    const int bid = blockIdx.x;

    if (bid < PA_BLKS) {
        // ----- A: jittered image, supertile = 16 m-rows x 512 px -----
        const int mt = bid / 80, ch = bid % 80;
        const int kbase = ch * 512;
        #pragma unroll
        for (int sub = 0; sub < 4; ++sub) {
            int r = sub*4 + w, m = mt*16 + r;
            bool mok = (m < 480);
            int b = 0, dy = 0, dx = 0;
            if (mok) {
                b = m / 60; int f = m % 60;
                dy = eye[(b*NJIT + f)*2 + 0];
                dx = eye[(b*NJIT + f)*2 + 1];
            }
            const float* imgb = img + (size_t)b*PP;
            #pragma unroll
            for (int h = 0; h < 2; ++h) {
                int ir = (kbase >> 8) + h + dy;
                bool ok = mok && (ir < HH);
                #pragma unroll
                for (int qq = 0; qq < 4; ++qq) {
                    int cc2 = qq*64 + l + dx;
                    float v = 0.f;
                    if (ok && cc2 < WW) v = imgb[ir*WW + cc2];   // coalesced
                    int X = FRX(r, h*256 + qq*64 + l);
                    lds[SWZ(X)] = f2fp8(v);
                }
            }
        }
        __syncthreads();
        unsigned char* outp = Ap + ((size_t)mt*KPTOT + ch*8)*1024;
        #pragma unroll
        for (int i = 0; i < 2; ++i) {
            int X = i*4096 + t*16;
            short8 v = *(const short8*)(lds + SWZ(X));
            *(short8*)(outp + X) = v;
        }
    } else {
        // ----- B: filters x BSCALE, supertile = 16 n-rows x 512 px -----
        const int bb = bid - PA_BLKS;
        const int nt = bb / 80, ch = bb % 80;
        const int kbase = ch * 512;
        #pragma unroll
        for (int sub = 0; sub < 4; ++sub) {
            int r = sub*4 + w, n = nt*16 + r;
            float4 va = make_float4(0.f,0.f,0.f,0.f), vb = va;
            if (n < CC) {
                const float* rowp = filt + (size_t)n*PP + kbase;
                va = *(const float4*)(rowp + l*4);
                vb = *(const float4*)(rowp + l*4 + 256);
            }
            unsigned da = (unsigned)f2fp8(va.x*BSCALE)
                        | ((unsigned)f2fp8(va.y*BSCALE) << 8)
                        | ((unsigned)f2fp8(va.z*BSCALE) << 16)
                        | ((unsigned)f2fp8(va.w*BSCALE) << 24);
            unsigned db = (unsigned)f2fp8(vb.x*BSCALE)
                        | ((unsigned)f2fp8(vb.y*BSCALE) << 8)
                        | ((unsigned)f2fp8(vb.z*BSCALE) << 16)
                        | ((unsigned)f2fp8(vb.w*BSCALE) << 24);
            int Xa = FRX(r, 4*l);
            *(unsigned*)(lds + SWZ(Xa)) = da;             // 2-way: free
            *(unsigned*)(lds + SWZ(Xa + (4 << 10))) = db; // pl+256 -> +4 ktpairs
        }
        __syncthreads();
        unsigned char* outp = Bp + ((size_t)nt*KPTOT + ch*8)*1024;
        #pragma unroll
        for (int i = 0; i < 2; ++i) {
            int X = i*4096 + t*16;
            short8 v = *(const short8*)(lds + SWZ(X));
            *(short8*)(outp + X) = v;
        }
    }
}

// ---------------------------------------------------------------------------
// gemm_f8: C += A x B in fp8 (e4m3), MFMA 16x16x32_fp8_fp8 (bf16 rate).
// BM=BN=128, BK=64 (one ktpair). 4 waves (2x2), wave = 64x64 (acc[4][4]).
// Per step: 16 gload16 (1KB each, linear LDS) + 8 ds_read_b128/wave + 32
// MFMA/wave. grid (4, 6, KSPLIT). Partials bf16.
// ---------------------------------------------------------------------------
__global__ __launch_bounds__(256) void gemm_f8(
    const unsigned char* __restrict__ Ap, const unsigned char* __restrict__ Bp,
    __hip_bfloat16* __restrict__ part)
{
    __shared__ unsigned char As[8192];   // 8 tiles x 1KB ktpair blocks
    __shared__ unsigned char Bs[8192];

    const int t = threadIdx.x, l = t & 63, w = t >> 6;
    const int mtile = blockIdx.x, ntile = blockIdx.y, z = blockIdx.z;
    const int wr = w >> 1, wc = w & 1;

    f32x4 acc[4][4] = {};

    for (int step = 0; step < NSTEP; ++step) {
        const size_t kp = (size_t)z*KPZ + step;
        const int tb0 = w*2, tb1 = w*2 + 1;
        gload16(Ap + ((size_t)(mtile*8 + tb0)*KPTOT + kp)*1024 + l*16, As + tb0*1024);
        gload16(Ap + ((size_t)(mtile*8 + tb1)*KPTOT + kp)*1024 + l*16, As + tb1*1024);
        gload16(Bp + ((size_t)(ntile*8 + tb0)*KPTOT + kp)*1024 + l*16, Bs + tb0*1024);
        gload16(Bp + ((size_t)(ntile*8 + tb1)*KPTOT + kp)*1024 + l*16, Bs + tb1*1024);
        __syncthreads();

        ulonglong2 a[4], b[4];
        #pragma unroll
        for (int i = 0; i < 4; ++i)
            a[i] = *(const ulonglong2*)(As + (wr*4 + i)*1024 + l*16);
        #pragma unroll
        for (int j = 0; j < 4; ++j)
            b[j] = *(const ulonglong2*)(Bs + (wc*4 + j)*1024 + l*16);
        #pragma unroll
        for (int i = 0; i < 4; ++i)
            #pragma unroll
            for (int j = 0; j < 4; ++j) {
                acc[i][j] = __builtin_amdgcn_mfma_f32_16x16x32_fp8_fp8(
                    (long long)a[i].x, (long long)b[j].x, acc[i][j], 0, 0, 0);
                acc[i][j] = __builtin_amdgcn_mfma_f32_16x16x32_fp8_fp8(
                    (long long)a[i].y, (long long)b[j].y, acc[i][j], 0, 0, 0);
            }
        __syncthreads();
    }

    // epilogue: C/D layout col = l&15, row = (l>>4)*4 + reg; bf16 partials
    const int rbase = (l >> 4)*4, cl = l & 15;
    #pragma unroll
    for (int i = 0; i < 4; ++i)
        #pragma unroll
        for (int j = 0; j < 4; ++j) {
            int m = mtile*128 + wr*64 + i*16 + rbase;
            int n = ntile*128 + wc*64 + j*16 + cl;
            __hip_bfloat16* p = part + ((size_t)z*MPAD + m)*NPAD + n;
            #pragma unroll
            for (int r = 0; r < 4; ++r)
                p[(size_t)r*NPAD] = __float2bfloat16(acc[i][j][r]);
        }
}

// ---------------------------------------------------------------------------
// build_spat: spat[b][fr][c] = history | (sum of bf16 partials) / BSCALE
// ---------------------------------------------------------------------------
__global__ __launch_bounds__(256) void build_spat(
    const float* __restrict__ hist, const __hip_bfloat16* __restrict__ part,
    float* __restrict__ spat)
{
    int idx = blockIdx.x*256 + threadIdx.x;
    if (idx >= BB*NFRM*CC) return;
    int c   = idx % CC;
    int rem = idx / CC;
    int fr  = rem % NFRM;
    int b   = rem / NFRM;
    float v;
    if (fr < NHIST) {
        v = hist[(b*NHIST + fr)*CC + c];
    } else {
        int m = b*NJIT + (fr - NHIST);
        v = 0.f;
        #pragma unroll
        for (int kp = 0; kp < KSPLIT; ++kp)
            v += __bfloat162float(part[((size_t)kp*MPAD + m)*NPAD + c]);
        v *= INV_BSCALE;
    }
    spat[idx] = v;
}

// ---------------------------------------------------------------------------
// conv_loss: per (b,c) gather+upsample -> depthwise conv (chunked-8 rolling
// window, all-static register indexing) -> loss partial. One wave per block.
// ---------------------------------------------------------------------------
__global__ __launch_bounds__(64) void conv_loss(
    const float* __restrict__ spat, const int* __restrict__ sel,
    const float* __restrict__ wts,  const float* __restrict__ tc,
    const float* __restrict__ fb,   const float* __restrict__ spk,
    const float* __restrict__ tmask, float* __restrict__ lpart)
{
    __shared__ float tcs[256];
    __shared__ float ups[864];   // index t + (t>>3): conflict-free sliding window

    const int lane = threadIdx.x;
    const int c = blockIdx.x;
    const int b = blockIdx.y;

    for (int k = lane; k < 256; k += 64)
        tcs[k] = (k < KK) ? tc[c*KK + k] : 0.f;

    const float* spb = spat + (size_t)b*NFRM*CC + c;
    for (int tt = lane; tt < 768; tt += 64) {
        float v = 0.f;
        if (tt < NBINS) {
            int base = (b*NBINS + tt)*2;
            int s0 = sel[base], s1 = sel[base+1];
            float w0 = wts[base], w1 = wts[base+1];
            v = w0 * spb[s0*CC] + w1 * spb[s1*CC];
        }
        ups[tt + (tt >> 3)] = v;
    }
    __syncthreads();

    const int t0 = lane * 8;
    float u[16];
    #pragma unroll
    for (int j = 0; j < 16; ++j) { int q = t0 + j; u[j] = ups[q + (q >> 3)]; }

    float acc[8] = {};
    #pragma unroll 4
    for (int kc = 0; kc < 248; kc += 8) {
        #pragma unroll
        for (int kk = 0; kk < 8; ++kk) {
            float w2 = tcs[kc + kk];
            #pragma unroll
            for (int j = 0; j < 8; ++j) acc[j] += w2 * u[kk + j];
        }
        #pragma unroll
        for (int j = 0; j < 8; ++j) u[j] = u[j + 8];
        #pragma unroll
        for (int j = 0; j < 8; ++j) {
            int q = t0 + kc + 16 + j;
            u[j + 8] = ups[q + (q >> 3)];
        }
    }
    #pragma unroll
    for (int kk = 0; kk < 8; ++kk) {
        float w2 = tcs[248 + kk];
        #pragma unroll
        for (int j = 0; j < 8; ++j) acc[j] += w2 * u[kk + j];
    }

    const size_t bc = (size_t)b*CC + c;
    const float* fbp = fb  + bc*(TOUT+1);
    const float* sp  = spk + bc*NBINS + KK;
    const float* tm  = tmask + (size_t)b*TOUT;
    float lsum = 0.f;
    #pragma unroll
    for (int j = 0; j < 8; ++j) {
        int tt = t0 + j;
        if (tt < TOUT) {
            float g  = acc[j] + fbp[tt];
            float sv = sp[tt];
            lsum += (__expf(g) - sv*g) * tm[tt];
        }
    }
    #pragma unroll
    for (int off = 32; off > 0; off >>= 1)
        lsum += __shfl_down(lsum, off);
    if (lane == 0) lpart[bc] = lsum * MAGIC;
}

__global__ __launch_bounds__(256) void reduce_out(
    const float* __restrict__ lpart, float* __restrict__ out)
{
    __shared__ float red[256];
    int b = blockIdx.x, t = threadIdx.x;
    float s = 0.f;
    for (int i = t; i < CC; i += 256) s += lpart[(size_t)b*CC + i];
    red[t] = s; __syncthreads();
    for (int o = 128; o > 0; o >>= 1) {
        if (t < o) red[t] += red[t+o];
        __syncthreads();
    }
    if (t == 0) out[b] = red[0];
}

extern "C" void kernel_launch(void* const* d_in, const int* in_sizes, int n_in,
                              void* d_out, int out_size, void* d_ws, size_t ws_size,
                              hipStream_t stream) {
    const float* image = (const float*)d_in[0];
    const float* spk   = (const float*)d_in[1];
    const int*   eye   = (const int*)d_in[2];
    const float* tmask = (const float*)d_in[3];
    const int*   sel   = (const int*)d_in[4];
    const float* wts   = (const float*)d_in[5];
    const float* filt  = (const float*)d_in[6];
    const float* tc    = (const float*)d_in[7];
    const float* fb    = (const float*)d_in[8];
    const float* hist  = (const float*)d_in[9];
    float* out = (float*)d_out;

    unsigned char* Ap = (unsigned char*)d_ws;                     // 20.97 MB fp8
    unsigned char* Bp = Ap + (size_t)32*KPTOT*1024;               // 31.46 MB fp8
    __hip_bfloat16* part = (__hip_bfloat16*)(Bp + (size_t)48*KPTOT*1024); // 15.7 MB
    float* spat  = (float*)(part + (size_t)KSPLIT*MPAD*NPAD);     // 2.0 MB
    float* lpart = spat + (size_t)BB*NFRM*CC;

    pack_ab  <<<dim3(PA_BLKS + PB_BLKS), 256, 0, stream>>>(image, eye, filt, Ap, Bp);
    gemm_f8  <<<dim3(4, 6, KSPLIT), 256, 0, stream>>>(Ap, Bp, part);
    build_spat<<<dim3((BB*NFRM*CC + 255)/256), 256, 0, stream>>>(hist, part, spat);
    conv_loss<<<dim3(CC, BB), 64, 0, stream>>>(spat, sel, wts, tc, fb, spk, tmask, lpart);
    reduce_out<<<dim3(BB), 256, 0, stream>>>(lpart, out);
}

// Round 10
// 126.940 us; speedup vs baseline: 1.1503x; 1.0263x over previous
//
#include <hip/hip_runtime.h>
#include <hip/hip_bf16.h>
#include <math.h>

// Problem constants
#define BB    8
#define HH    160
#define WW    256
#define CC    700
#define KK    250
#define NBINS 750
#define NHIST 30
#define NJIT  60
#define NFRM  90
#define PP    (HH*WW)      // 40960
#define TOUT  500
#define MAGIC (400.0f/750.0f)

// GEMM dims (fp8 path)
#define MPAD   512
#define NPAD   768
#define KPTOT  640         // K / 64  (ktpairs)
#define KSPLIT 20
#define KPZ    32          // ktpairs per z slice (2048 px)
#define NSTEP  32
#define BSCALE     64.0f   // filter pre-scale (keeps fp8 out of subnormals)
#define INV_BSCALE (1.0f/64.0f)
#define PA_BLKS (32*80)
#define PB_BLKS (48*80)

typedef __attribute__((ext_vector_type(8))) short short8;
typedef __attribute__((ext_vector_type(4))) float f32x4;

// Software fallback f32 -> OCP e4m3fn (RNE, FTZ below 2^-6, clamp +-448)
__device__ __forceinline__ unsigned char f2fp8(float x) {
    x = fminf(fmaxf(x, -440.f), 440.f);
    unsigned u = __builtin_bit_cast(unsigned, x);
    unsigned s = (u >> 24) & 0x80u;
    int e = (u >> 23) & 0xFF;
    if (e < 121) return (unsigned char)s;
    unsigned u2 = u + 0x7FFFFu + ((u >> 20) & 1u);
    int e2 = (u2 >> 23) & 0xFF;
    unsigned m = (u2 >> 20) & 7u;
    if (e2 > 135 || (e2 == 135 && m == 7u)) return (unsigned char)(s | 0x7E);
    return (unsigned char)(s | ((unsigned)(e2 - 120) << 3) | m);
}

// 4 x f32 -> packed fp8x4 (HW converter when available)
__device__ __forceinline__ unsigned pk4_fp8(float a, float b, float c, float d) {
#if __has_builtin(__builtin_amdgcn_cvt_pk_fp8_f32)
    int v = __builtin_amdgcn_cvt_pk_fp8_f32(a, b, 0, false);
    v = __builtin_amdgcn_cvt_pk_fp8_f32(c, d, v, true);
    return (unsigned)v;
#else
    return (unsigned)f2fp8(a) | ((unsigned)f2fp8(b) << 8)
         | ((unsigned)f2fp8(c) << 16) | ((unsigned)f2fp8(d) << 24);
#endif
}

__device__ __forceinline__ void gload16(const void* g, void* l) {
    __builtin_amdgcn_global_load_lds(
        (const __attribute__((address_space(1))) unsigned int*)g,
        (__attribute__((address_space(3))) unsigned int*)l, 16, 0, 0);
}

// LDS byte-offset swizzle (involution; XORs bits 8-10 into bank bits 4-6)
__device__ __forceinline__ int SWZ(int X) { return X ^ (((X >> 8) & 7) << 4); }

// Fragment-ready fp8 layout, per 16-row tile and ktpair (64 px) 1KB block:
//   byte(r, pl) = (pl>>6)*1024 + (((pl>>3)&3)*16 + r)*16 + ((pl>>5)&1)*8 + (pl&7)
__device__ __forceinline__ int FRX(int r, int pl) {
    return ((pl >> 6) << 10) | ((((pl >> 3) & 3) * 16 + r) << 4)
         | (((pl >> 5) & 1) << 3) | (pl & 7);
}

// ---------------------------------------------------------------------------
// pack_ab: A (jittered image) and B (filters x64) -> fp8 fragment layout via
// LDS transpose, HW cvt_pk_fp8. All LDS phases at the conflict floor
// (b32 scatter: 2 lanes/bank; b128 readback: uniform 8/bank).
// ---------------------------------------------------------------------------
__global__ __launch_bounds__(256) void pack_ab(
    const float* __restrict__ img, const int* __restrict__ eye,
    const float* __restrict__ filt,
    unsigned char* __restrict__ Ap, unsigned char* __restrict__ Bp)
{
    __shared__ unsigned char lds[8192];
    const int t = threadIdx.x, w = t >> 6, l = t & 63;
    const int bid = blockIdx.x;

    if (bid < PA_BLKS) {
        // ----- A: jittered image, supertile = 16 m-rows x 512 px -----
        const int mt = bid / 80, ch = bid % 80;
        const int kbase = ch * 512;
        #pragma unroll
        for (int sub = 0; sub < 4; ++sub) {
            int r = sub*4 + w, m = mt*16 + r;
            bool mok = (m < 480);
            int b = 0, dy = 0, dx = 0;
            if (mok) {
                b = m / 60; int f = m % 60;
                dy = eye[(b*NJIT + f)*2 + 0];
                dx = eye[(b*NJIT + f)*2 + 1];
            }
            const float* imgb = img + (size_t)b*PP;
            #pragma unroll
            for (int h = 0; h < 2; ++h) {
                int ir = (kbase >> 8) + h + dy;
                bool ok = mok && (ir < HH);
                const float* rowp = imgb + ir*WW + dx;   // row base (+dx)
                int c0 = 4*l;                            // px within 256-half
                float f0 = (ok && c0+0+dx < WW) ? rowp[c0+0] : 0.f;
                float f1 = (ok && c0+1+dx < WW) ? rowp[c0+1] : 0.f;
                float f2 = (ok && c0+2+dx < WW) ? rowp[c0+2] : 0.f;
                float f3 = (ok && c0+3+dx < WW) ? rowp[c0+3] : 0.f;
                unsigned d = pk4_fp8(f0, f1, f2, f3);
                int X = FRX(r, h*256 + c0);
                *(unsigned*)(lds + SWZ(X)) = d;
            }
        }
        __syncthreads();
        unsigned char* outp = Ap + ((size_t)mt*KPTOT + ch*8)*1024;
        #pragma unroll
        for (int i = 0; i < 2; ++i) {
            int X = i*4096 + t*16;
            short8 v = *(const short8*)(lds + SWZ(X));
            *(short8*)(outp + X) = v;
        }
    } else {
        // ----- B: filters x BSCALE, supertile = 16 n-rows x 512 px -----
        const int bb = bid - PA_BLKS;
        const int nt = bb / 80, ch = bb % 80;
        const int kbase = ch * 512;
        #pragma unroll
        for (int sub = 0; sub < 4; ++sub) {
            int r = sub*4 + w, n = nt*16 + r;
            float4 va = make_float4(0.f,0.f,0.f,0.f), vb = va;
            if (n < CC) {
                const float* rowp = filt + (size_t)n*PP + kbase;
                va = *(const float4*)(rowp + l*4);
                vb = *(const float4*)(rowp + l*4 + 256);
            }
            unsigned da = pk4_fp8(va.x*BSCALE, va.y*BSCALE, va.z*BSCALE, va.w*BSCALE);
            unsigned db = pk4_fp8(vb.x*BSCALE, vb.y*BSCALE, vb.z*BSCALE, vb.w*BSCALE);
            int Xa = FRX(r, 4*l);
            *(unsigned*)(lds + SWZ(Xa)) = da;             // 2-way: free
            *(unsigned*)(lds + SWZ(Xa + (4 << 10))) = db; // +256 px -> +4 ktpairs
        }
        __syncthreads();
        unsigned char* outp = Bp + ((size_t)nt*KPTOT + ch*8)*1024;
        #pragma unroll
        for (int i = 0; i < 2; ++i) {
            int X = i*4096 + t*16;
            short8 v = *(const short8*)(lds + SWZ(X));
            *(short8*)(outp + X) = v;
        }
    }
}

// ---------------------------------------------------------------------------
// gemm_f8: C += A x B in fp8 (e4m3), MFMA 16x16x32_fp8_fp8.
// BM=BN=128, BK=64 (one ktpair). 4 waves (2x2), wave = 64x64 (acc[4][4]).
// grid (4, 6, KSPLIT). Partials bf16.
// ---------------------------------------------------------------------------
__global__ __launch_bounds__(256) void gemm_f8(
    const unsigned char* __restrict__ Ap, const unsigned char* __restrict__ Bp,
    __hip_bfloat16* __restrict__ part)
{
    __shared__ unsigned char As[8192];   // 8 tiles x 1KB ktpair blocks
    __shared__ unsigned char Bs[8192];

    const int t = threadIdx.x, l = t & 63, w = t >> 6;
    const int mtile = blockIdx.x, ntile = blockIdx.y, z = blockIdx.z;
    const int wr = w >> 1, wc = w & 1;

    f32x4 acc[4][4] = {};

    for (int step = 0; step < NSTEP; ++step) {
        const size_t kp = (size_t)z*KPZ + step;
        const int tb0 = w*2, tb1 = w*2 + 1;
        gload16(Ap + ((size_t)(mtile*8 + tb0)*KPTOT + kp)*1024 + l*16, As + tb0*1024);
        gload16(Ap + ((size_t)(mtile*8 + tb1)*KPTOT + kp)*1024 + l*16, As + tb1*1024);
        gload16(Bp + ((size_t)(ntile*8 + tb0)*KPTOT + kp)*1024 + l*16, Bs + tb0*1024);
        gload16(Bp + ((size_t)(ntile*8 + tb1)*KPTOT + kp)*1024 + l*16, Bs + tb1*1024);
        __syncthreads();

        ulonglong2 a[4], b[4];
        #pragma unroll
        for (int i = 0; i < 4; ++i)
            a[i] = *(const ulonglong2*)(As + (wr*4 + i)*1024 + l*16);
        #pragma unroll
        for (int j = 0; j < 4; ++j)
            b[j] = *(const ulonglong2*)(Bs + (wc*4 + j)*1024 + l*16);
        #pragma unroll
        for (int i = 0; i < 4; ++i)
            #pragma unroll
            for (int j = 0; j < 4; ++j) {
                acc[i][j] = __builtin_amdgcn_mfma_f32_16x16x32_fp8_fp8(
                    (long long)a[i].x, (long long)b[j].x, acc[i][j], 0, 0, 0);
                acc[i][j] = __builtin_amdgcn_mfma_f32_16x16x32_fp8_fp8(
                    (long long)a[i].y, (long long)b[j].y, acc[i][j], 0, 0, 0);
            }
        __syncthreads();
    }

    // epilogue: C/D layout col = l&15, row = (l>>4)*4 + reg; bf16 partials
    const int rbase = (l >> 4)*4, cl = l & 15;
    #pragma unroll
    for (int i = 0; i < 4; ++i)
        #pragma unroll
        for (int j = 0; j < 4; ++j) {
            int m = mtile*128 + wr*64 + i*16 + rbase;
            int n = ntile*128 + wc*64 + j*16 + cl;
            __hip_bfloat16* p = part + ((size_t)z*MPAD + m)*NPAD + n;
            #pragma unroll
            for (int r = 0; r < 4; ++r)
                p[(size_t)r*NPAD] = __float2bfloat16(acc[i][j][r]);
        }
}

// ---------------------------------------------------------------------------
// build_spat: spat[b][fr][c] = history | (sum of bf16 partials) / BSCALE
// ---------------------------------------------------------------------------
__global__ __launch_bounds__(256) void build_spat(
    const float* __restrict__ hist, const __hip_bfloat16* __restrict__ part,
    float* __restrict__ spat)
{
    int idx = blockIdx.x*256 + threadIdx.x;
    if (idx >= BB*NFRM*CC) return;
    int c   = idx % CC;
    int rem = idx / CC;
    int fr  = rem % NFRM;
    int b   = rem / NFRM;
    float v;
    if (fr < NHIST) {
        v = hist[(b*NHIST + fr)*CC + c];
    } else {
        int m = b*NJIT + (fr - NHIST);
        v = 0.f;
        #pragma unroll
        for (int kp = 0; kp < KSPLIT; ++kp)
            v += __bfloat162float(part[((size_t)kp*MPAD + m)*NPAD + c]);
        v *= INV_BSCALE;
    }
    spat[idx] = v;
}

// ---------------------------------------------------------------------------
// conv_loss: per (b,c) gather+upsample -> depthwise conv (chunked-8 rolling
// window, all-static register indexing) -> loss partial. One wave per block.
// ---------------------------------------------------------------------------
__global__ __launch_bounds__(64) void conv_loss(
    const float* __restrict__ spat, const int* __restrict__ sel,
    const float* __restrict__ wts,  const float* __restrict__ tc,
    const float* __restrict__ fb,   const float* __restrict__ spk,
    const float* __restrict__ tmask, float* __restrict__ lpart)
{
    __shared__ float tcs[256];
    __shared__ float ups[864];   // index t + (t>>3): conflict-free sliding window

    const int lane = threadIdx.x;
    const int c = blockIdx.x;
    const int b = blockIdx.y;

    for (int k = lane; k < 256; k += 64)
        tcs[k] = (k < KK) ? tc[c*KK + k] : 0.f;

    const float* spb = spat + (size_t)b*NFRM*CC + c;
    for (int tt = lane; tt < 768; tt += 64) {
        float v = 0.f;
        if (tt < NBINS) {
            int base = (b*NBINS + tt)*2;
            int s0 = sel[base], s1 = sel[base+1];
            float w0 = wts[base], w1 = wts[base+1];
            v = w0 * spb[s0*CC] + w1 * spb[s1*CC];
        }
        ups[tt + (tt >> 3)] = v;
    }
    __syncthreads();

    const int t0 = lane * 8;
    float u[16];
    #pragma unroll
    for (int j = 0; j < 16; ++j) { int q = t0 + j; u[j] = ups[q + (q >> 3)]; }

    float acc[8] = {};
    #pragma unroll 4
    for (int kc = 0; kc < 248; kc += 8) {
        #pragma unroll
        for (int kk = 0; kk < 8; ++kk) {
            float w2 = tcs[kc + kk];
            #pragma unroll
            for (int j = 0; j < 8; ++j) acc[j] += w2 * u[kk + j];
        }
        #pragma unroll
        for (int j = 0; j < 8; ++j) u[j] = u[j + 8];
        #pragma unroll
        for (int j = 0; j < 8; ++j) {
            int q = t0 + kc + 16 + j;
            u[j + 8] = ups[q + (q >> 3)];
        }
    }
    #pragma unroll
    for (int kk = 0; kk < 8; ++kk) {
        float w2 = tcs[248 + kk];
        #pragma unroll
        for (int j = 0; j < 8; ++j) acc[j] += w2 * u[kk + j];
    }

    const size_t bc = (size_t)b*CC + c;
    const float* fbp = fb  + bc*(TOUT+1);
    const float* sp  = spk + bc*NBINS + KK;
    const float* tm  = tmask + (size_t)b*TOUT;
    float lsum = 0.f;
    #pragma unroll
    for (int j = 0; j < 8; ++j) {
        int tt = t0 + j;
        if (tt < TOUT) {
            float g  = acc[j] + fbp[tt];
            float sv = sp[tt];
            lsum += (__expf(g) - sv*g) * tm[tt];
        }
    }
    #pragma unroll
    for (int off = 32; off > 0; off >>= 1)
        lsum += __shfl_down(lsum, off);
    if (lane == 0) lpart[bc] = lsum * MAGIC;
}

__global__ __launch_bounds__(256) void reduce_out(
    const float* __restrict__ lpart, float* __restrict__ out)
{
    __shared__ float red[256];
    int b = blockIdx.x, t = threadIdx.x;
    float s = 0.f;
    for (int i = t; i < CC; i += 256) s += lpart[(size_t)b*CC + i];
    red[t] = s; __syncthreads();
    for (int o = 128; o > 0; o >>= 1) {
        if (t < o) red[t] += red[t+o];
        __syncthreads();
    }
    if (t == 0) out[b] = red[0];
}

extern "C" void kernel_launch(void* const* d_in, const int* in_sizes, int n_in,
                              void* d_out, int out_size, void* d_ws, size_t ws_size,
                              hipStream_t stream) {
    const float* image = (const float*)d_in[0];
    const float* spk   = (const float*)d_in[1];
    const int*   eye   = (const int*)d_in[2];
    const float* tmask = (const float*)d_in[3];
    const int*   sel   = (const int*)d_in[4];
    const float* wts   = (const float*)d_in[5];
    const float* filt  = (const float*)d_in[6];
    const float* tc    = (const float*)d_in[7];
    const float* fb    = (const float*)d_in[8];
    const float* hist  = (const float*)d_in[9];
    float* out = (float*)d_out;

    unsigned char* Ap = (unsigned char*)d_ws;                     // 20.97 MB fp8
    unsigned char* Bp = Ap + (size_t)32*KPTOT*1024;               // 31.46 MB fp8
    __hip_bfloat16* part = (__hip_bfloat16*)(Bp + (size_t)48*KPTOT*1024); // 15.7 MB
    float* spat  = (float*)(part + (size_t)KSPLIT*MPAD*NPAD);     // 2.0 MB
    float* lpart = spat + (size_t)BB*NFRM*CC;

    pack_ab  <<<dim3(PA_BLKS + PB_BLKS), 256, 0, stream>>>(image, eye, filt, Ap, Bp);
    gemm_f8  <<<dim3(4, 6, KSPLIT), 256, 0, stream>>>(Ap, Bp, part);
    build_spat<<<dim3((BB*NFRM*CC + 255)/256), 256, 0, stream>>>(hist, part, spat);
    conv_loss<<<dim3(CC, BB), 64, 0, stream>>>(spat, sel, wts, tc, fb, spk, tmask, lpart);
    reduce_out<<<dim3(BB), 256, 0, stream>>>(lpart, out);
}

// Round 11
// 120.983 us; speedup vs baseline: 1.2069x; 1.0492x over previous
//
#include <hip/hip_runtime.h>
#include <hip/hip_bf16.h>
#include <math.h>

// Problem constants
#define BB    8
#define HH    160
#define WW    256
#define CC    700
#define KK    250
#define NBINS 750
#define NHIST 30
#define NJIT  60
#define NFRM  90
#define PP    (HH*WW)      // 40960
#define TOUT  500
#define MAGIC (400.0f/750.0f)

// GEMM dims (fp8 path)
#define MPAD   512
#define NPAD   768
#define KPTOT  640         // K / 64  (ktpairs)
#define KSPLIT 32
#define KPZ    20          // ktpairs per z slice (1280 px)
#define BSCALE     64.0f   // filter pre-scale (keeps fp8 out of subnormals)
#define INV_BSCALE (1.0f/64.0f)
#define PA_BLKS (32*20)    // 640  (4 supertiles per block)
#define PB_BLKS (48*20)    // 960

typedef __attribute__((ext_vector_type(8))) short short8;
typedef __attribute__((ext_vector_type(4))) float f32x4;

// Software fallback f32 -> OCP e4m3fn (RNE, FTZ below 2^-6, clamp +-448)
__device__ __forceinline__ unsigned char f2fp8(float x) {
    x = fminf(fmaxf(x, -440.f), 440.f);
    unsigned u = __builtin_bit_cast(unsigned, x);
    unsigned s = (u >> 24) & 0x80u;
    int e = (u >> 23) & 0xFF;
    if (e < 121) return (unsigned char)s;
    unsigned u2 = u + 0x7FFFFu + ((u >> 20) & 1u);
    int e2 = (u2 >> 23) & 0xFF;
    unsigned m = (u2 >> 20) & 7u;
    if (e2 > 135 || (e2 == 135 && m == 7u)) return (unsigned char)(s | 0x7E);
    return (unsigned char)(s | ((unsigned)(e2 - 120) << 3) | m);
}

// 4 x f32 -> packed fp8x4 (HW converter when available)
__device__ __forceinline__ unsigned pk4_fp8(float a, float b, float c, float d) {
#if __has_builtin(__builtin_amdgcn_cvt_pk_fp8_f32)
    int v = __builtin_amdgcn_cvt_pk_fp8_f32(a, b, 0, false);
    v = __builtin_amdgcn_cvt_pk_fp8_f32(c, d, v, true);
    return (unsigned)v;
#else
    return (unsigned)f2fp8(a) | ((unsigned)f2fp8(b) << 8)
         | ((unsigned)f2fp8(c) << 16) | ((unsigned)f2fp8(d) << 24);
#endif
}

__device__ __forceinline__ void gload16(const void* g, void* l) {
    __builtin_amdgcn_global_load_lds(
        (const __attribute__((address_space(1))) unsigned int*)g,
        (__attribute__((address_space(3))) unsigned int*)l, 16, 0, 0);
}

// LDS byte-offset swizzle (involution; XORs bits 8-10 into bank bits 4-6)
__device__ __forceinline__ int SWZ(int X) { return X ^ (((X >> 8) & 7) << 4); }

// Fragment-ready fp8 layout, per 16-row tile and ktpair (64 px) 1KB block:
//   byte(r, pl) = (pl>>6)*1024 + (((pl>>3)&3)*16 + r)*16 + ((pl>>5)&1)*8 + (pl&7)
__device__ __forceinline__ int FRX(int r, int pl) {
    return ((pl >> 6) << 10) | ((((pl >> 3) & 3) * 16 + r) << 4)
         | (((pl >> 5) & 1) << 3) | (pl & 7);
}

// ---------------------------------------------------------------------------
// pack_ab: A (jittered image) and B (filters x64) -> fp8 fragment layout via
// LDS transpose, HW cvt_pk_fp8. 4 supertiles (16 rows x 512 px) per block.
// ---------------------------------------------------------------------------
__global__ __launch_bounds__(256) void pack_ab(
    const float* __restrict__ img, const int* __restrict__ eye,
    const float* __restrict__ filt,
    unsigned char* __restrict__ Ap, unsigned char* __restrict__ Bp)
{
    __shared__ unsigned char lds[8192];
    const int t = threadIdx.x, w = t >> 6, l = t & 63;
    const int bid = blockIdx.x;

    if (bid < PA_BLKS) {
        // ----- A: jittered image -----
        const int mt = bid / 20, ch4 = bid % 20;
        int rbv[4], rdy[4], rdx[4]; bool rok[4];
        #pragma unroll
        for (int sub = 0; sub < 4; ++sub) {
            int r = sub*4 + w, m = mt*16 + r;
            rok[sub] = (m < 480);
            int b = 0, dy = 0, dx = 0;
            if (rok[sub]) {
                b = m / 60; int f = m % 60;
                dy = eye[(b*NJIT + f)*2 + 0];
                dx = eye[(b*NJIT + f)*2 + 1];
            }
            rbv[sub] = b; rdy[sub] = dy; rdx[sub] = dx;
        }
        for (int q = 0; q < 4; ++q) {
            const int ch = ch4*4 + q;
            const int kbase = ch * 512;
            #pragma unroll
            for (int sub = 0; sub < 4; ++sub) {
                int r = sub*4 + w;
                const float* imgb = img + (size_t)rbv[sub]*PP;
                int dx = rdx[sub];
                #pragma unroll
                for (int h = 0; h < 2; ++h) {
                    int ir = (kbase >> 8) + h + rdy[sub];
                    bool ok = rok[sub] && (ir < HH);
                    const float* rowp = imgb + ir*WW + dx;
                    int c0 = 4*l;
                    float f0 = (ok && c0+0+dx < WW) ? rowp[c0+0] : 0.f;
                    float f1 = (ok && c0+1+dx < WW) ? rowp[c0+1] : 0.f;
                    float f2 = (ok && c0+2+dx < WW) ? rowp[c0+2] : 0.f;
                    float f3 = (ok && c0+3+dx < WW) ? rowp[c0+3] : 0.f;
                    unsigned d = pk4_fp8(f0, f1, f2, f3);
                    int X = FRX(r, h*256 + c0);
                    *(unsigned*)(lds + SWZ(X)) = d;
                }
            }
            __syncthreads();
            unsigned char* outp = Ap + ((size_t)mt*KPTOT + ch*8)*1024;
            #pragma unroll
            for (int i = 0; i < 2; ++i) {
                int X = i*4096 + t*16;
                short8 v = *(const short8*)(lds + SWZ(X));
                *(short8*)(outp + X) = v;
            }
            __syncthreads();
        }
    } else {
        // ----- B: filters x BSCALE -----
        const int bb = bid - PA_BLKS;
        const int nt = bb / 20, ch4 = bb % 20;
        for (int q = 0; q < 4; ++q) {
            const int ch = ch4*4 + q;
            const int kbase = ch * 512;
            #pragma unroll
            for (int sub = 0; sub < 4; ++sub) {
                int r = sub*4 + w, n = nt*16 + r;
                float4 va = make_float4(0.f,0.f,0.f,0.f), vb = va;
                if (n < CC) {
                    const float* rowp = filt + (size_t)n*PP + kbase;
                    va = *(const float4*)(rowp + l*4);
                    vb = *(const float4*)(rowp + l*4 + 256);
                }
                unsigned da = pk4_fp8(va.x*BSCALE, va.y*BSCALE, va.z*BSCALE, va.w*BSCALE);
                unsigned db = pk4_fp8(vb.x*BSCALE, vb.y*BSCALE, vb.z*BSCALE, vb.w*BSCALE);
                int Xa = FRX(r, 4*l);
                *(unsigned*)(lds + SWZ(Xa)) = da;
                *(unsigned*)(lds + SWZ(Xa + (4 << 10))) = db;
            }
            __syncthreads();
            unsigned char* outp = Bp + ((size_t)nt*KPTOT + ch*8)*1024;
            #pragma unroll
            for (int i = 0; i < 2; ++i) {
                int X = i*4096 + t*16;
                short8 v = *(const short8*)(lds + SWZ(X));
                *(short8*)(outp + X) = v;
            }
            __syncthreads();
        }
    }
}

// ---------------------------------------------------------------------------
// gemm_f8: C += A x B in fp8 (e4m3), MFMA 16x16x32_fp8_fp8.
// BM=BN=128, BK=64. 4 waves (2x2), wave = 64x64 (acc[4][4]).
// 768 blocks; bijective XCD swizzle: all 24 blocks of a z-slice land on
// XCD z&7 -> operand re-reads (A x6, B x4) become in-XCD L2 hits
// (per-z working set 2.5 MB < 4 MB L2).
// ---------------------------------------------------------------------------
__global__ __launch_bounds__(256) void gemm_f8(
    const unsigned char* __restrict__ Ap, const unsigned char* __restrict__ Bp,
    __hip_bfloat16* __restrict__ part)
{
    __shared__ unsigned char As[8192];   // 8 tiles x 1KB ktpair blocks
    __shared__ unsigned char Bs[8192];

    const int t = threadIdx.x, l = t & 63, w = t >> 6;
    const int bid = blockIdx.x;
    const int g   = bid >> 3;            // 0..95
    const int z   = (bid & 7) + 8*(g / 24);
    const int tt  = g % 24;
    const int mtile = tt / 6, ntile = tt % 6;
    const int wr = w >> 1, wc = w & 1;

    f32x4 acc[4][4] = {};

    for (int step = 0; step < KPZ; ++step) {
        const size_t kp = (size_t)z*KPZ + step;
        const int tb0 = w*2, tb1 = w*2 + 1;
        gload16(Ap + ((size_t)(mtile*8 + tb0)*KPTOT + kp)*1024 + l*16, As + tb0*1024);
        gload16(Ap + ((size_t)(mtile*8 + tb1)*KPTOT + kp)*1024 + l*16, As + tb1*1024);
        gload16(Bp + ((size_t)(ntile*8 + tb0)*KPTOT + kp)*1024 + l*16, Bs + tb0*1024);
        gload16(Bp + ((size_t)(ntile*8 + tb1)*KPTOT + kp)*1024 + l*16, Bs + tb1*1024);
        __syncthreads();

        ulonglong2 a[4], b[4];
        #pragma unroll
        for (int i = 0; i < 4; ++i)
            a[i] = *(const ulonglong2*)(As + (wr*4 + i)*1024 + l*16);
        #pragma unroll
        for (int j = 0; j < 4; ++j)
            b[j] = *(const ulonglong2*)(Bs + (wc*4 + j)*1024 + l*16);
        #pragma unroll
        for (int i = 0; i < 4; ++i)
            #pragma unroll
            for (int j = 0; j < 4; ++j) {
                acc[i][j] = __builtin_amdgcn_mfma_f32_16x16x32_fp8_fp8(
                    (long long)a[i].x, (long long)b[j].x, acc[i][j], 0, 0, 0);
                acc[i][j] = __builtin_amdgcn_mfma_f32_16x16x32_fp8_fp8(
                    (long long)a[i].y, (long long)b[j].y, acc[i][j], 0, 0, 0);
            }
        __syncthreads();
    }

    // epilogue: C/D layout col = l&15, row = (l>>4)*4 + reg; bf16 partials
    const int rbase = (l >> 4)*4, cl = l & 15;
    #pragma unroll
    for (int i = 0; i < 4; ++i)
        #pragma unroll
        for (int j = 0; j < 4; ++j) {
            int m = mtile*128 + wr*64 + i*16 + rbase;
            int n = ntile*128 + wc*64 + j*16 + cl;
            __hip_bfloat16* p = part + ((size_t)z*MPAD + m)*NPAD + n;
            #pragma unroll
            for (int r = 0; r < 4; ++r)
                p[(size_t)r*NPAD] = __float2bfloat16(acc[i][j][r]);
        }
}

// ---------------------------------------------------------------------------
// build_spat: spat[b][fr][c] = history | (sum of bf16 partials) / BSCALE
// ---------------------------------------------------------------------------
__global__ __launch_bounds__(256) void build_spat(
    const float* __restrict__ hist, const __hip_bfloat16* __restrict__ part,
    float* __restrict__ spat)
{
    int idx = blockIdx.x*256 + threadIdx.x;
    if (idx >= BB*NFRM*CC) return;
    int c   = idx % CC;
    int rem = idx / CC;
    int fr  = rem % NFRM;
    int b   = rem / NFRM;
    float v;
    if (fr < NHIST) {
        v = hist[(b*NHIST + fr)*CC + c];
    } else {
        int m = b*NJIT + (fr - NHIST);
        v = 0.f;
        #pragma unroll
        for (int kp = 0; kp < KSPLIT; ++kp)
            v += __bfloat162float(part[((size_t)kp*MPAD + m)*NPAD + c]);
        v *= INV_BSCALE;
    }
    spat[idx] = v;
}

// ---------------------------------------------------------------------------
// conv_loss: per (b,c) gather+upsample -> depthwise conv (chunked-8 rolling
// window, all-static register indexing) -> loss partial. One wave per block.
// ---------------------------------------------------------------------------
__global__ __launch_bounds__(64) void conv_loss(
    const float* __restrict__ spat, const int* __restrict__ sel,
    const float* __restrict__ wts,  const float* __restrict__ tc,
    const float* __restrict__ fb,   const float* __restrict__ spk,
    const float* __restrict__ tmask, float* __restrict__ lpart)
{
    __shared__ float tcs[256];
    __shared__ float ups[864];   // index t + (t>>3): conflict-free sliding window

    const int lane = threadIdx.x;
    const int c = blockIdx.x;
    const int b = blockIdx.y;

    for (int k = lane; k < 256; k += 64)
        tcs[k] = (k < KK) ? tc[c*KK + k] : 0.f;

    const float* spb = spat + (size_t)b*NFRM*CC + c;
    for (int tt = lane; tt < 768; tt += 64) {
        float v = 0.f;
        if (tt < NBINS) {
            int base = (b*NBINS + tt)*2;
            int s0 = sel[base], s1 = sel[base+1];
            float w0 = wts[base], w1 = wts[base+1];
            v = w0 * spb[s0*CC] + w1 * spb[s1*CC];
        }
        ups[tt + (tt >> 3)] = v;
    }
    __syncthreads();

    const int t0 = lane * 8;
    float u[16];
    #pragma unroll
    for (int j = 0; j < 16; ++j) { int q = t0 + j; u[j] = ups[q + (q >> 3)]; }

    float acc[8] = {};
    #pragma unroll 4
    for (int kc = 0; kc < 248; kc += 8) {
        #pragma unroll
        for (int kk = 0; kk < 8; ++kk) {
            float w2 = tcs[kc + kk];
            #pragma unroll
            for (int j = 0; j < 8; ++j) acc[j] += w2 * u[kk + j];
        }
        #pragma unroll
        for (int j = 0; j < 8; ++j) u[j] = u[j + 8];
        #pragma unroll
        for (int j = 0; j < 8; ++j) {
            int q = t0 + kc + 16 + j;
            u[j + 8] = ups[q + (q >> 3)];
        }
    }
    #pragma unroll
    for (int kk = 0; kk < 8; ++kk) {
        float w2 = tcs[248 + kk];
        #pragma unroll
        for (int j = 0; j < 8; ++j) acc[j] += w2 * u[kk + j];
    }

    const size_t bc = (size_t)b*CC + c;
    const float* fbp = fb  + bc*(TOUT+1);
    const float* sp  = spk + bc*NBINS + KK;
    const float* tm  = tmask + (size_t)b*TOUT;
    float lsum = 0.f;
    #pragma unroll
    for (int j = 0; j < 8; ++j) {
        int tt = t0 + j;
        if (tt < TOUT) {
            float g  = acc[j] + fbp[tt];
            float sv = sp[tt];
            lsum += (__expf(g) - sv*g) * tm[tt];
        }
    }
    #pragma unroll
    for (int off = 32; off > 0; off >>= 1)
        lsum += __shfl_down(lsum, off);
    if (lane == 0) lpart[bc] = lsum * MAGIC;
}

__global__ __launch_bounds__(256) void reduce_out(
    const float* __restrict__ lpart, float* __restrict__ out)
{
    __shared__ float red[256];
    int b = blockIdx.x, t = threadIdx.x;
    float s = 0.f;
    for (int i = t; i < CC; i += 256) s += lpart[(size_t)b*CC + i];
    red[t] = s; __syncthreads();
    for (int o = 128; o > 0; o >>= 1) {
        if (t < o) red[t] += red[t+o];
        __syncthreads();
    }
    if (t == 0) out[b] = red[0];
}

extern "C" void kernel_launch(void* const* d_in, const int* in_sizes, int n_in,
                              void* d_out, int out_size, void* d_ws, size_t ws_size,
                              hipStream_t stream) {
    const float* image = (const float*)d_in[0];
    const float* spk   = (const float*)d_in[1];
    const int*   eye   = (const int*)d_in[2];
    const float* tmask = (const float*)d_in[3];
    const int*   sel   = (const int*)d_in[4];
    const float* wts   = (const float*)d_in[5];
    const float* filt  = (const float*)d_in[6];
    const float* tc    = (const float*)d_in[7];
    const float* fb    = (const float*)d_in[8];
    const float* hist  = (const float*)d_in[9];
    float* out = (float*)d_out;

    unsigned char* Ap = (unsigned char*)d_ws;                     // 20.97 MB fp8
    unsigned char* Bp = Ap + (size_t)32*KPTOT*1024;               // 31.46 MB fp8
    __hip_bfloat16* part = (__hip_bfloat16*)(Bp + (size_t)48*KPTOT*1024); // 25.2 MB
    float* spat  = (float*)(part + (size_t)KSPLIT*MPAD*NPAD);     // 2.0 MB
    float* lpart = spat + (size_t)BB*NFRM*CC;

    pack_ab  <<<dim3(PA_BLKS + PB_BLKS), 256, 0, stream>>>(image, eye, filt, Ap, Bp);
    gemm_f8  <<<dim3(8*96), 256, 0, stream>>>(Ap, Bp, part);
    build_spat<<<dim3((BB*NFRM*CC + 255)/256), 256, 0, stream>>>(hist, part, spat);
    conv_loss<<<dim3(CC, BB), 64, 0, stream>>>(spat, sel, wts, tc, fb, spk, tmask, lpart);
    reduce_out<<<dim3(BB), 256, 0, stream>>>(lpart, out);
}